// Round 1
// baseline (594.760 us; speedup 1.0000x reference)
//
#include <hip/hip_runtime.h>
#include <hip/hip_bf16.h>

typedef float f32x4 __attribute__((ext_vector_type(4)));
typedef __bf16 bf16x8 __attribute__((ext_vector_type(8)));
typedef int v4i __attribute__((ext_vector_type(4)));

#define NPRE (45L * 384 * 128)   // elements per transposed weight array

// ---- prep: transpose + fp32->bf16 cast of both weight tensors into d_ws ----
// wpreT[k][o][i]  = w_pre[k][i][o]    (o=0..383, i=0..127)
// wpostT[k][n][d] = w_post[k][d][n]   (n=0..127, d=0..383)
__global__ __launch_bounds__(256) void prep_weights(
    const float* __restrict__ w_pre, const float* __restrict__ w_post,
    __bf16* __restrict__ wpreT, __bf16* __restrict__ wpostT) {
  long e = (long)blockIdx.x * 256 + threadIdx.x;
  if (e < NPRE) {
    int i = (int)(e & 127);
    long rest = e >> 7;
    int o = (int)(rest % 384);
    int k = (int)(rest / 384);
    wpreT[e] = (__bf16)w_pre[((long)k * 128 + i) * 384 + o];
  } else {
    long e2 = e - NPRE;
    int d = (int)(e2 % 384);
    long rest = e2 / 384;
    int n = (int)(rest & 127);
    int k = (int)(rest >> 7);
    wpostT[e2] = (__bf16)w_post[((long)k * 384 + d) * 128 + n];
  }
}

// ---- main fused kernel ----
// grid: (125 row-tiles, 45 bands), block: 256 threads = 4 waves.
// Each block: 64 rows (b,t) x one band.
//   Xg(64x128) -> [GEMM1 chunked by o(128)] -> H chunk(64x128 bf16 in LDS)
//   -> [GEMM2 accumulate over d] -> Y(64x128) -> scattered contiguous stores.
__global__ __launch_bounds__(256) void band_mlp(
    const float* __restrict__ x,
    const float* __restrict__ b_pre, const float* __restrict__ b_post,
    const __bf16* __restrict__ wpreT, const __bf16* __restrict__ wpostT,
    float* __restrict__ out) {
  // LDS layout (bytes):
  //   sA   [0,      17408)  : 64 x 136 bf16   (Xg tile, +8 pad)
  //   sBuf [17408,  35840)  : 128 x 72 bf16   (weight slab, +8 pad)
  //   sH   [35840,  53248)  : 64 x 136 bf16   (H chunk)
  //   sY   aliases sA+sBuf  : 64 x 132 f32 = 33792 B (epilogue only)
  __shared__ alignas(16) char smem[53248];
  __bf16 (*sA)[136] = reinterpret_cast<__bf16(*)[136]>(smem);
  __bf16 (*sBuf)[72] = reinterpret_cast<__bf16(*)[72]>(smem + 17408);
  __bf16 (*sH)[136] = reinterpret_cast<__bf16(*)[136]>(smem + 35840);
  float (*sY)[132] = reinterpret_cast<float(*)[132]>(smem);

  const int tid = threadIdx.x;
  const int k = blockIdx.y;       // band
  const int rt = blockIdx.x;      // row tile (64 rows)

  // band geometry: len = min(4+k,32), f0 = prefix sum (closed form)
  const int f0 = (k <= 28) ? (k * (k + 7)) / 2 : 522 + 32 * (k - 29);
  int len = (4 + k < 32) ? 4 + k : 32;
  if (len > 1025 - f0) len = 1025 - f0;   // band 44 -> 23

  // ---- stage gathered Xg tile: sA[row][w*4+c] = x[b][c][t][f0+w] (bf16) ----
  {
    const int row = tid >> 2, c = tid & 3;
    const int m = rt * 64 + row;
    const int b = m / 1000, t = m % 1000;
    const float* px = x + (((long)(b * 4 + c) * 1000 + t) * 1025 + f0);
#pragma unroll
    for (int w = 0; w < 32; ++w) {
      float v = (w < len) ? px[w] : 0.0f;
      sA[row][w * 4 + c] = (__bf16)v;
    }
  }

  const int lane = tid & 63;
  const int wid = tid >> 6;
  const int l15 = lane & 15;
  const int q = lane >> 4;
  const int m0 = wid * 16;        // this wave's 16 rows

  f32x4 accY[8];
#pragma unroll
  for (int i = 0; i < 8; ++i) accY[i] = (f32x4){0.f, 0.f, 0.f, 0.f};

  const __bf16* wpre_k = wpreT + (long)k * 384 * 128;
  const __bf16* wpost_k = wpostT + (long)k * 128 * 384;

  for (int nc = 0; nc < 3; ++nc) {            // o-chunks of 128 (D=384)
    f32x4 accH[8];
#pragma unroll
    for (int i = 0; i < 8; ++i) accH[i] = (f32x4){0.f, 0.f, 0.f, 0.f};

    // ---- GEMM1 chunk: H[:,nc*128..+128) = Xg @ Wpre, K=i(128) in slabs of 64
    for (int ko = 0; ko < 128; ko += 64) {
      __syncthreads();  // prior sBuf users done
      // stage sBuf[o_l][0..63] = wpreT[k][nc*128+o_l][ko..ko+64)
#pragma unroll
      for (int it = 0; it < 4; ++it) {
        int e = it * 256 + tid;
        int o_l = e >> 3, seg = e & 7;
        const v4i* src = reinterpret_cast<const v4i*>(
            wpre_k + ((long)(nc * 128 + o_l) * 128 + ko + seg * 8));
        *reinterpret_cast<v4i*>(&sBuf[o_l][seg * 8]) = *src;
      }
      __syncthreads();
#pragma unroll
      for (int kk = 0; kk < 64; kk += 32) {
        bf16x8 a = *reinterpret_cast<const bf16x8*>(&sA[m0 + l15][ko + kk + q * 8]);
#pragma unroll
        for (int nt = 0; nt < 8; ++nt) {
          bf16x8 bf = *reinterpret_cast<const bf16x8*>(&sBuf[nt * 16 + l15][kk + q * 8]);
          accH[nt] = __builtin_amdgcn_mfma_f32_16x16x32_bf16(a, bf, accH[nt], 0, 0, 0);
        }
      }
    }

    // ---- H chunk -> LDS as bf16 (C-layout -> A-layout transform), + b_pre
    {
      const float* bp = b_pre + k * 384 + nc * 128;
#pragma unroll
      for (int nt = 0; nt < 8; ++nt) {
        float bias = bp[nt * 16 + l15];
#pragma unroll
        for (int r = 0; r < 4; ++r) {
          sH[m0 + q * 4 + r][nt * 16 + l15] = (__bf16)(accH[nt][r] + bias);
        }
      }
    }

    // ---- GEMM2 partial: Y += H_chunk @ Wpost[d in chunk], K=d(128) slabs of 64
    for (int ko2 = 0; ko2 < 128; ko2 += 64) {
      __syncthreads();  // sBuf free AND sH writes visible
#pragma unroll
      for (int it = 0; it < 4; ++it) {
        int e = it * 256 + tid;
        int n_l = e >> 3, seg = e & 7;
        const v4i* src = reinterpret_cast<const v4i*>(
            wpost_k + ((long)n_l * 384 + nc * 128 + ko2 + seg * 8));
        *reinterpret_cast<v4i*>(&sBuf[n_l][seg * 8]) = *src;
      }
      __syncthreads();
#pragma unroll
      for (int kk = 0; kk < 64; kk += 32) {
        bf16x8 a = *reinterpret_cast<const bf16x8*>(&sH[m0 + l15][ko2 + kk + q * 8]);
#pragma unroll
        for (int nt = 0; nt < 8; ++nt) {
          bf16x8 bf = *reinterpret_cast<const bf16x8*>(&sBuf[nt * 16 + l15][kk + q * 8]);
          accY[nt] = __builtin_amdgcn_mfma_f32_16x16x32_bf16(a, bf, accY[nt], 0, 0, 0);
        }
      }
    }
  }

  // ---- epilogue: Y + b_post -> sY (f32) -> coalesced scattered stores ----
  __syncthreads();  // all reads of sA/sBuf done; sY aliases them
  {
    const float* bp = b_post + k * 128;
#pragma unroll
    for (int nt = 0; nt < 8; ++nt) {
      int n = nt * 16 + l15;
      float bias = bp[n];
#pragma unroll
      for (int r = 0; r < 4; ++r) {
        sY[m0 + q * 4 + r][n] = accY[nt][r] + bias;
      }
    }
  }
  __syncthreads();
  {
    const int grp = tid >> 5, l32 = tid & 31;
    for (int it = 0; it < 32; ++it) {
      int idx = it * 8 + grp;          // 0..255 over (row, c)
      int row = idx >> 2, c = idx & 3;
      int m = rt * 64 + row;
      int b = m / 1000, t = m % 1000;
      if (l32 < len) {
        out[((long)(b * 4 + c) * 1000 + t) * 1025 + f0 + l32] = sY[row][l32 * 4 + c];
      }
    }
  }
}

extern "C" void kernel_launch(void* const* d_in, const int* in_sizes, int n_in,
                              void* d_out, int out_size, void* d_ws, size_t ws_size,
                              hipStream_t stream) {
  const float* x      = (const float*)d_in[0];
  const float* w_pre  = (const float*)d_in[1];
  const float* b_pre  = (const float*)d_in[2];
  const float* w_post = (const float*)d_in[3];
  const float* b_post = (const float*)d_in[4];
  float* out = (float*)d_out;

  __bf16* wpreT  = (__bf16*)d_ws;
  __bf16* wpostT = (__bf16*)((char*)d_ws + NPRE * 2);

  // 2 * 2,211,840 elements / 256 = 17280 blocks
  prep_weights<<<17280, 256, 0, stream>>>(w_pre, w_post, wpreT, wpostT);
  band_mlp<<<dim3(125, 45), 256, 0, stream>>>(x, b_pre, b_post, wpreT, wpostT, out);
}

// Round 2
// 508.480 us; speedup vs baseline: 1.1697x; 1.1697x over previous
//
#include <hip/hip_runtime.h>
#include <hip/hip_bf16.h>

typedef float f32x4 __attribute__((ext_vector_type(4)));
typedef __bf16 bf16x8 __attribute__((ext_vector_type(8)));
typedef unsigned int u32;
typedef const __attribute__((address_space(1))) u32* gas_u32;
typedef __attribute__((address_space(3))) u32* las_u32;

#define NPRE (45L * 384 * 128)   // elements per transposed weight array

// ---- prep: transpose + cast + index-permute both weight tensors ----
// wpreT[k][o][i'] = w_pre[k][perm(i')][o],   perm(i') = (i'&31)*4 + (i'>>5)
//   (i' = c*32+w ordering so x-gather/stores are contiguous)
// wpostT[k][s][n'][pl] = w_post[k][ d(p) ][ perm(n') ],  p = s*128+pl
//   d(p) permutes the GEMM2 K-order so the A-operand (H) is consumed
//   directly from MFMA C-layout registers: for within=p&31, q=within>>3,
//   j=within&7:  d = (p&~31) + 16*(j>>2) + 4*q + (j&3)
__global__ __launch_bounds__(256) void prep_weights(
    const float* __restrict__ w_pre, const float* __restrict__ w_post,
    __bf16* __restrict__ wpreT, __bf16* __restrict__ wpostT) {
  long e = (long)blockIdx.x * 256 + threadIdx.x;
  if (e < NPRE) {
    int ip = (int)(e & 127);
    long rest = e >> 7;
    int o = (int)(rest % 384);
    int k = (int)(rest / 384);
    int i = ((ip & 31) << 2) + (ip >> 5);
    wpreT[e] = (__bf16)w_pre[((long)k * 128 + i) * 384 + o];
  } else {
    long e2 = e - NPRE;
    int pl = (int)(e2 & 127);
    long r1 = e2 >> 7;
    int np = (int)(r1 & 127);
    long r2 = r1 >> 7;
    int s = (int)(r2 % 3);
    int k = (int)(r2 / 3);
    int p = s * 128 + pl;
    int within = p & 31, q2 = within >> 3, j = within & 7;
    int d = (p & ~31) + ((j >> 2) << 4) + (q2 << 2) + (j & 3);
    int i_n = ((np & 31) << 2) + (np >> 5);
    wpostT[e2] = (__bf16)w_post[((long)k * 384 + d) * 128 + i_n];
  }
}

// ---- fused band MLP: grid 5625 1D (XCD-affine band mapping), 256 thr ----
__global__ __launch_bounds__(256, 3) void band_mlp(
    const float* __restrict__ x,
    const float* __restrict__ b_pre, const float* __restrict__ b_post,
    const __bf16* __restrict__ wpreT, const __bf16* __restrict__ wpostT,
    float* __restrict__ out) {
  __shared__ __bf16 sA[64 * 128];    // 16 KB, granule-XOR-swizzled Xg tile
  __shared__ __bf16 sW[128 * 128];   // 32 KB, granule-XOR-swizzled weight slab

  const int tid = threadIdx.x;
  const int bid = blockIdx.x;

  // band/tile decode: bands 0..39 pinned to XCD k%8; bands 40..44 spread
  int k, tile;
  if (bid < 5000) {
    int s = bid & 7, seq = bid >> 3;
    int bi = seq / 125;
    tile = seq - bi * 125;
    k = bi * 8 + s;
  } else {
    int r = bid - 5000;
    k = 40 + r / 125;
    tile = r - (k - 40) * 125;
  }

  const int f0 = (k <= 28) ? (k * (k + 7)) / 2 : 490 + 32 * (k - 28);
  int len = (4 + k < 32) ? 4 + k : 32;
  if (len > 1025 - f0) len = 1025 - f0;

  // ---- stage Xg tile: sA[row][c*32+w] (swizzled), coalesced 128B loads ----
  {
    const int grp = tid >> 5, l32 = tid & 31;
    for (int it = 0; it < 32; ++it) {
      int idx = it * 8 + grp;            // 0..255 = (row, c)
      int row = idx >> 2, c = idx & 3;
      int m = tile * 64 + row;
      int b = m / 1000, t = m - b * 1000;
      float v = (l32 < len) ? x[((long)(b * 4 + c) * 1000 + t) * 1025 + f0 + l32] : 0.0f;
      int col = c * 32 + l32;
      int gr = (col >> 3) ^ (row & 7);
      sA[row * 128 + gr * 8 + (col & 7)] = (__bf16)v;
    }
  }

  const int lane = tid & 63;
  const int wid = tid >> 6;
  const int l15 = lane & 15;
  const int q = lane >> 4;
  const int m0 = wid * 16;           // this wave's 16 rows
  const int swz = l15 & 7;           // read-side granule XOR

  const __bf16* wpre_k  = wpreT  + (long)k * 384 * 128;
  const __bf16* wpost_k = wpostT + (long)k * 384 * 128;

  // async slab loader: 128x128 bf16, XOR-swizzle applied via per-lane SOURCE
  // address (LDS dest must stay wave-uniform-base + lane*16)
  auto load_slab = [&](const __bf16* src) {
#pragma unroll
    for (int u = 0; u < 8; ++u) {
      int lin = u * 256 + tid;         // 16B chunk id
      int row = lin >> 4, gp = lin & 15;
      int gl = gp ^ (row & 7);
      __builtin_amdgcn_global_load_lds((gas_u32)(const void*)(src + row * 128 + gl * 8),
                                       (las_u32)(void*)(sW + lin * 8), 16, 0, 0);
    }
  };

  bf16x8 hA[12];                     // H in registers = GEMM2 A-frags, 48 VGPR

  // ---- GEMM1: H^T = Wpre^T(o x i) * Xg^T(i x m), K=i=128 per slab ----
  for (int s = 0; s < 3; ++s) {
    __syncthreads();                 // prior sW readers done (and sA staged)
    load_slab(wpre_k + s * 128 * 128);
    f32x4 bias[8];
#pragma unroll
    for (int ot = 0; ot < 8; ++ot)
      bias[ot] = *(const f32x4*)(b_pre + k * 384 + s * 128 + ot * 16 + q * 4);
    f32x4 accH[8];
#pragma unroll
    for (int ot = 0; ot < 8; ++ot) accH[ot] = (f32x4){0.f, 0.f, 0.f, 0.f};
    __syncthreads();                 // slab loads complete
#pragma unroll
    for (int ch = 0; ch < 4; ++ch) {
      bf16x8 xb = *(const bf16x8*)(sA + (m0 + l15) * 128 + (((ch * 4 + q) ^ swz) * 8));
#pragma unroll
      for (int ot = 0; ot < 8; ++ot) {
        bf16x8 wa = *(const bf16x8*)(sW + (ot * 16 + l15) * 128 + (((ch * 4 + q) ^ swz) * 8));
        accH[ot] = __builtin_amdgcn_mfma_f32_16x16x32_bf16(wa, xb, accH[ot], 0, 0, 0);
      }
    }
    // bias + pack into A-frag registers: lane holds H[m0+l15][OT*16+q*4+r]
#pragma unroll
    for (int ot = 0; ot < 8; ++ot) {
      int OT = s * 8 + ot;
#pragma unroll
      for (int r = 0; r < 4; ++r)
        hA[OT >> 1][(OT & 1) * 4 + r] = (__bf16)(accH[ot][r] + bias[ot][r]);
    }
  }

  // ---- GEMM2: Y = H(m x d) * Wpost(d x n'), A-frags straight from hA ----
  f32x4 accY[8];
#pragma unroll
  for (int i = 0; i < 8; ++i) accY[i] = (f32x4){0.f, 0.f, 0.f, 0.f};

  for (int s = 0; s < 3; ++s) {
    __syncthreads();                 // prior sW readers done
    load_slab(wpost_k + s * 128 * 128);
    __syncthreads();                 // slab loads complete
#pragma unroll
    for (int cl = 0; cl < 4; ++cl) {
      int c = s * 4 + cl;
      bf16x8 a2 = hA[c];
#pragma unroll
      for (int nt = 0; nt < 8; ++nt) {
        bf16x8 wb = *(const bf16x8*)(sW + (nt * 16 + l15) * 128 + (((cl * 4 + q) ^ swz) * 8));
        accY[nt] = __builtin_amdgcn_mfma_f32_16x16x32_bf16(a2, wb, accY[nt], 0, 0, 0);
      }
    }
  }

  // ---- epilogue: bias + scattered (64B-coalesced) stores from registers ----
  float bp[8];
#pragma unroll
  for (int nt = 0; nt < 8; ++nt) {
    int n = nt * 16 + l15;
    bp[nt] = b_post[k * 128 + ((n & 31) << 2) + (n >> 5)];
  }
  long obase[4];
#pragma unroll
  for (int r = 0; r < 4; ++r) {
    int m = tile * 64 + m0 + q * 4 + r;
    int b = m / 1000, t = m - b * 1000;
    obase[r] = (long)(b * 4) * 1025000 + (long)t * 1025 + f0;
  }
#pragma unroll
  for (int nt = 0; nt < 8; ++nt) {
    int n = nt * 16 + l15;
    int w = n & 31, c = n >> 5;
    if (w < len) {
#pragma unroll
      for (int r = 0; r < 4; ++r)
        out[obase[r] + (long)c * 1025000 + w] = accY[nt][r] + bp[nt];
    }
  }
}

extern "C" void kernel_launch(void* const* d_in, const int* in_sizes, int n_in,
                              void* d_out, int out_size, void* d_ws, size_t ws_size,
                              hipStream_t stream) {
  const float* x      = (const float*)d_in[0];
  const float* w_pre  = (const float*)d_in[1];
  const float* b_pre  = (const float*)d_in[2];
  const float* w_post = (const float*)d_in[3];
  const float* b_post = (const float*)d_in[4];
  float* out = (float*)d_out;

  __bf16* wpreT  = (__bf16*)d_ws;
  __bf16* wpostT = (__bf16*)((char*)d_ws + NPRE * 2);

  prep_weights<<<17280, 256, 0, stream>>>(w_pre, w_post, wpreT, wpostT);
  band_mlp<<<5625, 256, 0, stream>>>(x, b_pre, b_post, wpreT, wpostT, out);
}